// Round 1
// baseline (46.661 us; speedup 1.0000x reference)
//
#include <hip/hip_runtime.h>
#include <math.h>

#define BSZ 512
#define DSZ 512
#define MARGIN 0.4f
#define ALPHA 1.0f

// ---------------- Kernel 1: row L2-normalize -----------------
// grid = 512 blocks (one per row), block = 256 threads.
__global__ void rll_normalize(const float* __restrict__ emb,
                              float* __restrict__ x,
                              float* __restrict__ sq) {
    const int row = blockIdx.x;
    const int tid = threadIdx.x;             // 0..255
    const float2 v = ((const float2*)(emb + (size_t)row * DSZ))[tid];
    float s = v.x * v.x + v.y * v.y;
    // wave64 reduce
    #pragma unroll
    for (int off = 32; off > 0; off >>= 1) s += __shfl_down(s, off);
    __shared__ float wpart[4];
    const int wave = tid >> 6, lane = tid & 63;
    if (lane == 0) wpart[wave] = s;
    __syncthreads();
    __shared__ float inv_s;
    if (tid == 0) {
        float t = wpart[0] + wpart[1] + wpart[2] + wpart[3];
        float m = fmaxf(sqrtf(t), 1e-12f);
        inv_s = 1.0f / m;
        sq[row] = t / (m * m);               // ||x||^2 of normalized row
    }
    __syncthreads();
    float inv = inv_s;
    float2 o;
    o.x = v.x * inv;
    o.y = v.y * inv;
    ((float2*)(x + (size_t)row * DSZ))[tid] = o;
}

// ---------------- Kernel 2: dist = sqrt(max(sq_i+sq_j-2*x.x^T, 0)) ----
#define TILE 16
__global__ void rll_dist(const float* __restrict__ x,
                         const float* __restrict__ sq,
                         float* __restrict__ dist) {
    __shared__ float As[TILE][TILE + 1];
    __shared__ float Bs[TILE][TILE + 1];
    const int tx = threadIdx.x, ty = threadIdx.y;
    const int row = blockIdx.y * TILE + ty;
    const int col = blockIdx.x * TILE + tx;
    float acc = 0.f;
    for (int kt = 0; kt < DSZ; kt += TILE) {
        As[ty][tx] = x[(size_t)row * DSZ + kt + tx];
        Bs[ty][tx] = x[(size_t)(blockIdx.x * TILE + ty) * DSZ + kt + tx];
        __syncthreads();
        #pragma unroll
        for (int k = 0; k < TILE; ++k) acc += As[ty][k] * Bs[tx][k];
        __syncthreads();
    }
    float d2 = sq[row] + sq[col] - 2.0f * acc;
    dist[(size_t)row * BSZ + col] = sqrtf(fmaxf(d2, 0.0f));
}

// ---------------- Kernel 3: ranked-list counting + loss ---------------
// grid = 512 blocks (one per anchor i), block = 256 threads (4 waves).
__global__ void rll_count(const float* __restrict__ dist,
                          const int* __restrict__ labels,
                          float* __restrict__ out) {
    __shared__ float dsh[BSZ];
    __shared__ int   lsh[BSZ];
    __shared__ int   pos[BSZ];
    __shared__ int   npos;
    __shared__ float wsum[4];
    const int i = blockIdx.x;
    const int tid = threadIdx.x;
    if (tid == 0) npos = 0;
    for (int j = tid; j < BSZ; j += 256) {
        dsh[j] = dist[(size_t)i * BSZ + j];
        lsh[j] = labels[j];
    }
    __syncthreads();
    const int li = lsh[i];
    for (int j = tid; j < BSZ; j += 256) {
        if (j != i && lsh[j] == li) {
            int idx = atomicAdd(&npos, 1);
            pos[idx] = j;
        }
    }
    if (tid < 4) wsum[tid] = 0.f;
    __syncthreads();
    const int wave = tid >> 6, lane = tid & 63;
    const int np = npos;
    float acc = 0.f;
    for (int p = wave; p < np; p += 4) {
        const int j = pos[p];
        const float thr = dsh[j] + MARGIN;
        int cnt = 0;
        #pragma unroll
        for (int kk = 0; kk < BSZ / 64; ++kk) {
            const int k = lane + kk * 64;
            cnt += (lsh[k] != li && dsh[k] < thr) ? 1 : 0;
        }
        #pragma unroll
        for (int off = 32; off > 0; off >>= 1) cnt += __shfl_down(cnt, off);
        if (lane == 0 && cnt > 0) acc += log1pf((float)cnt);
    }
    if (lane == 0) wsum[wave] = acc;
    __syncthreads();
    if (tid == 0) {
        float t = (wsum[0] + wsum[1] + wsum[2] + wsum[3]) *
                  (ALPHA / (512.0f + 1e-8f));
        if (t != 0.0f) atomicAdd(out, t);
    }
}

extern "C" void kernel_launch(void* const* d_in, const int* in_sizes, int n_in,
                              void* d_out, int out_size, void* d_ws, size_t ws_size,
                              hipStream_t stream) {
    const float* emb    = (const float*)d_in[0];
    const int*   labels = (const int*)d_in[1];
    float* out = (float*)d_out;

    // workspace layout: x (512*512 f32) | sq (512 f32) | dist (512*512 f32)
    float* x    = (float*)d_ws;
    float* sq   = x + (size_t)BSZ * DSZ;
    float* dist = sq + BSZ;

    hipMemsetAsync(out, 0, sizeof(float), stream);

    rll_normalize<<<BSZ, 256, 0, stream>>>(emb, x, sq);

    dim3 bd(TILE, TILE);
    dim3 gd(BSZ / TILE, BSZ / TILE);
    rll_dist<<<gd, bd, 0, stream>>>(x, sq, dist);

    rll_count<<<BSZ, 256, 0, stream>>>(dist, labels, out);
}

// Round 2
// 43.938 us; speedup vs baseline: 1.0620x; 1.0620x over previous
//
#include <hip/hip_runtime.h>
#include <math.h>

#define BSZ 512
#define DSZ 512
#define MARGIN 0.4f
#define ALPHA 1.0f

// ---------------- Kernel 1: row L2-normalize -----------------
// grid = 512 blocks (one per row), block = 256 threads.
// Block 0 / thread 0 also zeroes the output scalar (stream order makes
// this visible to rll_count, which runs later on the same stream).
__global__ void rll_normalize(const float* __restrict__ emb,
                              float* __restrict__ x,
                              float* __restrict__ sq,
                              float* __restrict__ out) {
    const int row = blockIdx.x;
    const int tid = threadIdx.x;             // 0..255
    if (row == 0 && tid == 0) out[0] = 0.0f;
    const float2 v = ((const float2*)(emb + (size_t)row * DSZ))[tid];
    float s = v.x * v.x + v.y * v.y;
    // wave64 reduce
    #pragma unroll
    for (int off = 32; off > 0; off >>= 1) s += __shfl_down(s, off);
    __shared__ float wpart[4];
    const int wave = tid >> 6, lane = tid & 63;
    if (lane == 0) wpart[wave] = s;
    __syncthreads();
    __shared__ float inv_s;
    if (tid == 0) {
        float t = wpart[0] + wpart[1] + wpart[2] + wpart[3];
        float m = fmaxf(sqrtf(t), 1e-12f);
        inv_s = 1.0f / m;
        sq[row] = t / (m * m);               // ||x||^2 of normalized row
    }
    __syncthreads();
    float inv = inv_s;
    float2 o;
    o.x = v.x * inv;
    o.y = v.y * inv;
    ((float2*)(x + (size_t)row * DSZ))[tid] = o;
}

// ---------------- Kernel 2: dist = sqrt(max(sq_i+sq_j-2*x.x^T, 0)) ----
#define TILE 16
__global__ void rll_dist(const float* __restrict__ x,
                         const float* __restrict__ sq,
                         float* __restrict__ dist) {
    __shared__ float As[TILE][TILE + 1];
    __shared__ float Bs[TILE][TILE + 1];
    const int tx = threadIdx.x, ty = threadIdx.y;
    const int row = blockIdx.y * TILE + ty;
    const int col = blockIdx.x * TILE + tx;
    float acc = 0.f;
    for (int kt = 0; kt < DSZ; kt += TILE) {
        As[ty][tx] = x[(size_t)row * DSZ + kt + tx];
        Bs[ty][tx] = x[(size_t)(blockIdx.x * TILE + ty) * DSZ + kt + tx];
        __syncthreads();
        #pragma unroll
        for (int k = 0; k < TILE; ++k) acc += As[ty][k] * Bs[tx][k];
        __syncthreads();
    }
    float d2 = sq[row] + sq[col] - 2.0f * acc;
    dist[(size_t)row * BSZ + col] = sqrtf(fmaxf(d2, 0.0f));
}

// ---------------- Kernel 3: ranked-list counting + loss ---------------
// grid = 512 blocks (one per anchor i), block = 256 threads (4 waves).
__global__ void rll_count(const float* __restrict__ dist,
                          const int* __restrict__ labels,
                          float* __restrict__ out) {
    __shared__ float dsh[BSZ];
    __shared__ int   lsh[BSZ];
    __shared__ int   pos[BSZ];
    __shared__ int   npos;
    __shared__ float wsum[4];
    const int i = blockIdx.x;
    const int tid = threadIdx.x;
    if (tid == 0) npos = 0;
    for (int j = tid; j < BSZ; j += 256) {
        dsh[j] = dist[(size_t)i * BSZ + j];
        lsh[j] = labels[j];
    }
    __syncthreads();
    const int li = lsh[i];
    for (int j = tid; j < BSZ; j += 256) {
        if (j != i && lsh[j] == li) {
            int idx = atomicAdd(&npos, 1);
            pos[idx] = j;
        }
    }
    if (tid < 4) wsum[tid] = 0.f;
    __syncthreads();
    const int wave = tid >> 6, lane = tid & 63;
    const int np = npos;
    float acc = 0.f;
    for (int p = wave; p < np; p += 4) {
        const int j = pos[p];
        const float thr = dsh[j] + MARGIN;
        int cnt = 0;
        #pragma unroll
        for (int kk = 0; kk < BSZ / 64; ++kk) {
            const int k = lane + kk * 64;
            cnt += (lsh[k] != li && dsh[k] < thr) ? 1 : 0;
        }
        #pragma unroll
        for (int off = 32; off > 0; off >>= 1) cnt += __shfl_down(cnt, off);
        if (lane == 0 && cnt > 0) acc += log1pf((float)cnt);
    }
    if (lane == 0) wsum[wave] = acc;
    __syncthreads();
    if (tid == 0) {
        float t = (wsum[0] + wsum[1] + wsum[2] + wsum[3]) *
                  (ALPHA / (512.0f + 1e-8f));
        if (t != 0.0f) atomicAdd(out, t);
    }
}

extern "C" void kernel_launch(void* const* d_in, const int* in_sizes, int n_in,
                              void* d_out, int out_size, void* d_ws, size_t ws_size,
                              hipStream_t stream) {
    const float* emb    = (const float*)d_in[0];
    const int*   labels = (const int*)d_in[1];
    float* out = (float*)d_out;

    // workspace layout: x (512*512 f32) | sq (512 f32) | dist (512*512 f32)
    float* x    = (float*)d_ws;
    float* sq   = x + (size_t)BSZ * DSZ;
    float* dist = sq + BSZ;

    rll_normalize<<<BSZ, 256, 0, stream>>>(emb, x, sq, out);

    dim3 bd(TILE, TILE);
    dim3 gd(BSZ / TILE, BSZ / TILE);
    rll_dist<<<gd, bd, 0, stream>>>(x, sq, dist);

    rll_count<<<BSZ, 256, 0, stream>>>(dist, labels, out);
}

// Round 3
// 42.177 us; speedup vs baseline: 1.1063x; 1.0417x over previous
//
#include <hip/hip_runtime.h>
#include <math.h>

#define BSZ 512
#define DSZ 512
#define MARGIN 0.4f
#define ALPHA 1.0f

// ---------------- Kernel 1: row inverse norms + zero output -----------
// grid = 512 blocks (one per row), block = 64 threads (1 wave).
__global__ __launch_bounds__(64) void rll_norms(const float* __restrict__ emb,
                                                float* __restrict__ inv_norm,
                                                float* __restrict__ out) {
    const int row = blockIdx.x;
    const int lane = threadIdx.x;            // 0..63
    if (row == 0 && lane == 0) out[0] = 0.0f;
    const float4* p = (const float4*)(emb + (size_t)row * DSZ);
    const float4 v0 = p[lane];
    const float4 v1 = p[lane + 64];
    float s = v0.x * v0.x + v0.y * v0.y + v0.z * v0.z + v0.w * v0.w
            + v1.x * v1.x + v1.y * v1.y + v1.z * v1.z + v1.w * v1.w;
    #pragma unroll
    for (int off = 32; off > 0; off >>= 1) s += __shfl_down(s, off);
    if (lane == 0) {
        inv_norm[row] = 1.0f / fmaxf(sqrtf(s), 1e-12f);
    }
}

// ---------------- Kernel 2: dist = sqrt(max(2 - 2*<x_i,x_j>, 0)) ------
// Register-tiled Gram: BM=BN=32, BK=32, 64 threads (8x8), 4x4 micro-tile.
// A stored transposed in LDS (As[k][m]) so fragment reads are float4.
#define BM 32
#define BK 32
__global__ __launch_bounds__(64) void rll_dist(const float* __restrict__ emb,
                                               const float* __restrict__ inv_norm,
                                               float* __restrict__ dist) {
    __shared__ float As[BK][BM];   // [k][m]
    __shared__ float Bs[BK][BM];   // [k][n]
    const int tid = threadIdx.x;                 // 0..63
    const int brow = blockIdx.y * BM;
    const int bcol = blockIdx.x * BM;
    // staging role: row within tile + which half of the k-slab
    const int sm  = tid & 31;
    const int sk0 = (tid >> 5) * 16;             // 0 or 16
    const float inv_a = inv_norm[brow + sm];
    const float inv_b = inv_norm[bcol + sm];
    // compute role: 8x8 thread grid, 4x4 outputs each
    const int ty = tid >> 3;                     // 0..7
    const int tx = tid & 7;                      // 0..7

    float acc[4][4];
    #pragma unroll
    for (int i = 0; i < 4; ++i)
        #pragma unroll
        for (int j = 0; j < 4; ++j) acc[i][j] = 0.f;

    for (int kt = 0; kt < DSZ; kt += BK) {
        // issue global loads early (overlap with previous tile's compute)
        const float4* pa = (const float4*)(emb + (size_t)(brow + sm) * DSZ + kt + sk0);
        const float4* pb = (const float4*)(emb + (size_t)(bcol + sm) * DSZ + kt + sk0);
        float va[16], vb[16];
        *(float4*)&va[0]  = pa[0];
        *(float4*)&va[4]  = pa[1];
        *(float4*)&va[8]  = pa[2];
        *(float4*)&va[12] = pa[3];
        *(float4*)&vb[0]  = pb[0];
        *(float4*)&vb[4]  = pb[1];
        *(float4*)&vb[8]  = pb[2];
        *(float4*)&vb[12] = pb[3];
        __syncthreads();   // previous tile's LDS reads done
        #pragma unroll
        for (int q = 0; q < 16; ++q) {
            As[sk0 + q][sm] = va[q] * inv_a;
            Bs[sk0 + q][sm] = vb[q] * inv_b;
        }
        __syncthreads();
        #pragma unroll
        for (int k = 0; k < BK; ++k) {
            const float4 av = *(const float4*)&As[k][ty << 2];
            const float4 bv = *(const float4*)&Bs[k][tx << 2];
            float a_[4] = {av.x, av.y, av.z, av.w};
            float b_[4] = {bv.x, bv.y, bv.z, bv.w};
            #pragma unroll
            for (int i = 0; i < 4; ++i)
                #pragma unroll
                for (int j = 0; j < 4; ++j)
                    acc[i][j] += a_[i] * b_[j];
        }
    }
    // epilogue: d2 = 2 - 2*dot (rows are unit-norm), dist = sqrt(max(d2,0))
    #pragma unroll
    for (int i = 0; i < 4; ++i) {
        float4 o;
        o.x = sqrtf(fmaxf(2.0f - 2.0f * acc[i][0], 0.0f));
        o.y = sqrtf(fmaxf(2.0f - 2.0f * acc[i][1], 0.0f));
        o.z = sqrtf(fmaxf(2.0f - 2.0f * acc[i][2], 0.0f));
        o.w = sqrtf(fmaxf(2.0f - 2.0f * acc[i][3], 0.0f));
        *(float4*)&dist[(size_t)(brow + (ty << 2) + i) * BSZ + bcol + (tx << 2)] = o;
    }
}

// ---------------- Kernel 3: ranked-list counting + loss ---------------
// grid = 512 blocks (one per anchor i), block = 256 threads (4 waves).
__global__ void rll_count(const float* __restrict__ dist,
                          const int* __restrict__ labels,
                          float* __restrict__ out) {
    __shared__ float dsh[BSZ];
    __shared__ int   lsh[BSZ];
    __shared__ int   pos[BSZ];
    __shared__ int   npos;
    __shared__ float wsum[4];
    const int i = blockIdx.x;
    const int tid = threadIdx.x;
    if (tid == 0) npos = 0;
    for (int j = tid; j < BSZ; j += 256) {
        dsh[j] = dist[(size_t)i * BSZ + j];
        lsh[j] = labels[j];
    }
    __syncthreads();
    const int li = lsh[i];
    for (int j = tid; j < BSZ; j += 256) {
        if (j != i && lsh[j] == li) {
            int idx = atomicAdd(&npos, 1);
            pos[idx] = j;
        }
    }
    if (tid < 4) wsum[tid] = 0.f;
    __syncthreads();
    const int wave = tid >> 6, lane = tid & 63;
    const int np = npos;
    float acc = 0.f;
    for (int p = wave; p < np; p += 4) {
        const int j = pos[p];
        const float thr = dsh[j] + MARGIN;
        int cnt = 0;
        #pragma unroll
        for (int kk = 0; kk < BSZ / 64; ++kk) {
            const int k = lane + kk * 64;
            cnt += (lsh[k] != li && dsh[k] < thr) ? 1 : 0;
        }
        #pragma unroll
        for (int off = 32; off > 0; off >>= 1) cnt += __shfl_down(cnt, off);
        if (lane == 0 && cnt > 0) acc += log1pf((float)cnt);
    }
    if (lane == 0) wsum[wave] = acc;
    __syncthreads();
    if (tid == 0) {
        float t = (wsum[0] + wsum[1] + wsum[2] + wsum[3]) *
                  (ALPHA / (512.0f + 1e-8f));
        if (t != 0.0f) atomicAdd(out, t);
    }
}

extern "C" void kernel_launch(void* const* d_in, const int* in_sizes, int n_in,
                              void* d_out, int out_size, void* d_ws, size_t ws_size,
                              hipStream_t stream) {
    const float* emb    = (const float*)d_in[0];
    const int*   labels = (const int*)d_in[1];
    float* out = (float*)d_out;

    // workspace layout: inv_norm (512 f32) | dist (512*512 f32)
    float* inv_norm = (float*)d_ws;
    float* dist     = inv_norm + BSZ;

    rll_norms<<<BSZ, 64, 0, stream>>>(emb, inv_norm, out);

    dim3 gd(BSZ / BM, BSZ / BM);
    rll_dist<<<gd, 64, 0, stream>>>(emb, inv_norm, dist);

    rll_count<<<BSZ, 256, 0, stream>>>(dist, labels, out);
}

// Round 4
// 37.779 us; speedup vs baseline: 1.2351x; 1.1164x over previous
//
#include <hip/hip_runtime.h>
#include <math.h>

#define BSZ 512
#define DSZ 512
#define MARGIN 0.4f
#define ALPHA 1.0f

// ---------------- Kernel 1: fused norms + dist tile -------------------
// dist = sqrt(max(2 - 2*dot_raw(i,j)*inv_i*inv_j, 0))
// Register-tiled Gram: BM=BN=32, BK=32, 64 threads (8x8), 4x4 micro-tile.
// Row sum-of-squares accumulated during staging (raw values staged).
#define BM 32
#define BK 32
__global__ __launch_bounds__(64) void rll_dist(const float* __restrict__ emb,
                                               float* __restrict__ dist) {
    __shared__ float As[BK][BM];   // [k][m], raw values
    __shared__ float Bs[BK][BM];   // [k][n], raw values
    __shared__ float sA[2][BM];    // per-row sumsq partials (A rows)
    __shared__ float sB[2][BM];    // per-row sumsq partials (B rows)
    const int tid = threadIdx.x;                 // 0..63
    const int brow = blockIdx.y * BM;
    const int bcol = blockIdx.x * BM;
    // staging role: row within tile + which half of the k-slab
    const int sm  = tid & 31;
    const int shalf = tid >> 5;                  // 0 or 1
    const int sk0 = shalf * 16;                  // 0 or 16
    // compute role: 8x8 thread grid, 4x4 outputs each
    const int ty = tid >> 3;                     // 0..7
    const int tx = tid & 7;                      // 0..7

    float acc[4][4];
    #pragma unroll
    for (int i = 0; i < 4; ++i)
        #pragma unroll
        for (int j = 0; j < 4; ++j) acc[i][j] = 0.f;
    float ssa = 0.f, ssb = 0.f;                  // sumsq partials

    for (int kt = 0; kt < DSZ; kt += BK) {
        const float4* pa = (const float4*)(emb + (size_t)(brow + sm) * DSZ + kt + sk0);
        const float4* pb = (const float4*)(emb + (size_t)(bcol + sm) * DSZ + kt + sk0);
        float va[16], vb[16];
        *(float4*)&va[0]  = pa[0];
        *(float4*)&va[4]  = pa[1];
        *(float4*)&va[8]  = pa[2];
        *(float4*)&va[12] = pa[3];
        *(float4*)&vb[0]  = pb[0];
        *(float4*)&vb[4]  = pb[1];
        *(float4*)&vb[8]  = pb[2];
        *(float4*)&vb[12] = pb[3];
        __syncthreads();   // previous tile's LDS reads done
        #pragma unroll
        for (int q = 0; q < 16; ++q) {
            As[sk0 + q][sm] = va[q];
            Bs[sk0 + q][sm] = vb[q];
            ssa += va[q] * va[q];
            ssb += vb[q] * vb[q];
        }
        __syncthreads();
        #pragma unroll
        for (int k = 0; k < BK; ++k) {
            const float4 av = *(const float4*)&As[k][ty << 2];
            const float4 bv = *(const float4*)&Bs[k][tx << 2];
            float a_[4] = {av.x, av.y, av.z, av.w};
            float b_[4] = {bv.x, bv.y, bv.z, bv.w};
            #pragma unroll
            for (int i = 0; i < 4; ++i)
                #pragma unroll
                for (int j = 0; j < 4; ++j)
                    acc[i][j] += a_[i] * b_[j];
        }
    }
    // publish per-row sumsq, combine the two k-half partials
    sA[shalf][sm] = ssa;
    sB[shalf][sm] = ssb;
    __syncthreads();
    float inv_a[4], inv_b[4];
    #pragma unroll
    for (int i = 0; i < 4; ++i) {
        const int m = (ty << 2) + i;
        const int n = (tx << 2) + i;
        inv_a[i] = 1.0f / fmaxf(sqrtf(sA[0][m] + sA[1][m]), 1e-12f);
        inv_b[i] = 1.0f / fmaxf(sqrtf(sB[0][n] + sB[1][n]), 1e-12f);
    }
    #pragma unroll
    for (int i = 0; i < 4; ++i) {
        float4 o;
        o.x = sqrtf(fmaxf(2.0f - 2.0f * acc[i][0] * inv_a[i] * inv_b[0], 0.0f));
        o.y = sqrtf(fmaxf(2.0f - 2.0f * acc[i][1] * inv_a[i] * inv_b[1], 0.0f));
        o.z = sqrtf(fmaxf(2.0f - 2.0f * acc[i][2] * inv_a[i] * inv_b[2], 0.0f));
        o.w = sqrtf(fmaxf(2.0f - 2.0f * acc[i][3] * inv_a[i] * inv_b[3], 0.0f));
        *(float4*)&dist[(size_t)(brow + (ty << 2) + i) * BSZ + bcol + (tx << 2)] = o;
    }
}

// ---------------- Kernel 2: ranked-list counting, per-block partial ----
// grid = 512 blocks (one per anchor i), block = 256 threads (4 waves).
// NO global atomics: each block stores its partial sum to partial[i].
__global__ void rll_count(const float* __restrict__ dist,
                          const int* __restrict__ labels,
                          float* __restrict__ partial) {
    __shared__ float dsh[BSZ];
    __shared__ int   lsh[BSZ];
    __shared__ int   pos[BSZ];
    __shared__ int   npos;
    __shared__ float wsum[4];
    const int i = blockIdx.x;
    const int tid = threadIdx.x;
    if (tid == 0) npos = 0;
    for (int j = tid; j < BSZ; j += 256) {
        dsh[j] = dist[(size_t)i * BSZ + j];
        lsh[j] = labels[j];
    }
    __syncthreads();
    const int li = lsh[i];
    for (int j = tid; j < BSZ; j += 256) {
        if (j != i && lsh[j] == li) {
            int idx = atomicAdd(&npos, 1);
            pos[idx] = j;
        }
    }
    if (tid < 4) wsum[tid] = 0.f;
    __syncthreads();
    const int wave = tid >> 6, lane = tid & 63;
    const int np = npos;
    float acc = 0.f;
    for (int p = wave; p < np; p += 4) {
        const int j = pos[p];
        const float thr = dsh[j] + MARGIN;
        int cnt = 0;
        #pragma unroll
        for (int kk = 0; kk < BSZ / 64; ++kk) {
            const int k = lane + kk * 64;
            cnt += (lsh[k] != li && dsh[k] < thr) ? 1 : 0;
        }
        #pragma unroll
        for (int off = 32; off > 0; off >>= 1) cnt += __shfl_down(cnt, off);
        if (lane == 0 && cnt > 0) acc += log1pf((float)cnt);
    }
    if (lane == 0) wsum[wave] = acc;
    __syncthreads();
    if (tid == 0) {
        // unconditional store: d_ws is poisoned, every slot must be written
        partial[i] = wsum[0] + wsum[1] + wsum[2] + wsum[3];
    }
}

// ---------------- Kernel 3: final 512-element reduce ------------------
// 1 block, 64 threads. Writes out[0] directly (no accumulation).
__global__ __launch_bounds__(64) void rll_reduce(const float* __restrict__ partial,
                                                 float* __restrict__ out) {
    const int lane = threadIdx.x;
    float s = 0.f;
    #pragma unroll
    for (int q = 0; q < BSZ / 64; ++q) s += partial[lane + q * 64];
    #pragma unroll
    for (int off = 32; off > 0; off >>= 1) s += __shfl_down(s, off);
    if (lane == 0) out[0] = s * (ALPHA / (512.0f + 1e-8f));
}

extern "C" void kernel_launch(void* const* d_in, const int* in_sizes, int n_in,
                              void* d_out, int out_size, void* d_ws, size_t ws_size,
                              hipStream_t stream) {
    const float* emb    = (const float*)d_in[0];
    const int*   labels = (const int*)d_in[1];
    float* out = (float*)d_out;

    // workspace layout: dist (512*512 f32) | partial (512 f32)
    float* dist    = (float*)d_ws;
    float* partial = dist + (size_t)BSZ * BSZ;

    dim3 gd(BSZ / BM, BSZ / BM);
    rll_dist<<<gd, 64, 0, stream>>>(emb, dist);

    rll_count<<<BSZ, 256, 0, stream>>>(dist, labels, partial);

    rll_reduce<<<1, 64, 0, stream>>>(partial, out);
}

// Round 5
// 30.527 us; speedup vs baseline: 1.5285x; 1.2376x over previous
//
#include <hip/hip_runtime.h>
#include <math.h>

#define BSZ 512
#define DSZ 512
#define MARGIN 0.4f
#define ALPHA 1.0f

// ---------------- Kernel 1: fused norms + Gram + dist -----------------
// dist = sqrt(max(2 - 2*dot_raw(i,j)*inv_i*inv_j, 0))
// 256 blocks (one 32x32 output tile each), 256 threads = 4 waves.
// Wave w handles k in [w*128, w*128+128) staged in its OWN LDS slab:
// no __syncthreads in the main loop, waves run independently.
__global__ __launch_bounds__(256) void rll_dist(const float* __restrict__ emb,
                                                float* __restrict__ dist,
                                                int* __restrict__ counter) {
    __shared__ float As[4][32][32];    // [wave][k][m], raw values
    __shared__ float Bs[4][32][32];    // [wave][k][n]
    __shared__ float comb[4][64][16];  // accumulator combine buffer
    __shared__ float sAq[4][2][32];    // per-wave, per-khalf row sumsq
    __shared__ float sBq[4][2][32];
    const int tid = threadIdx.x;
    const int w = tid >> 6;                      // wave 0..3
    const int l = tid & 63;                      // lane
    if (blockIdx.x == 0 && blockIdx.y == 0 && tid == 0) counter[0] = 0;
    const int brow = blockIdx.y * 32;
    const int bcol = blockIdx.x * 32;
    // staging role within wave: row + which 16-wide half of the 32-k slab
    const int sm = l & 31;
    const int shalf = l >> 5;
    const int sk0 = shalf * 16;
    // compute role within wave: 8x8 grid, 4x4 outputs
    const int ty = l >> 3;
    const int tx = l & 7;

    float acc[4][4];
    #pragma unroll
    for (int i = 0; i < 4; ++i)
        #pragma unroll
        for (int j = 0; j < 4; ++j) acc[i][j] = 0.f;
    float ssa = 0.f, ssb = 0.f;

    #pragma unroll
    for (int r = 0; r < 4; ++r) {
        const int kt = w * 128 + r * 32;
        const float4* pa = (const float4*)(emb + (size_t)(brow + sm) * DSZ + kt + sk0);
        const float4* pb = (const float4*)(emb + (size_t)(bcol + sm) * DSZ + kt + sk0);
        float va[16], vb[16];
        *(float4*)&va[0]  = pa[0];
        *(float4*)&va[4]  = pa[1];
        *(float4*)&va[8]  = pa[2];
        *(float4*)&va[12] = pa[3];
        *(float4*)&vb[0]  = pb[0];
        *(float4*)&vb[4]  = pb[1];
        *(float4*)&vb[8]  = pb[2];
        *(float4*)&vb[12] = pb[3];
        #pragma unroll
        for (int q = 0; q < 16; ++q) {
            As[w][sk0 + q][sm] = va[q];
            Bs[w][sk0 + q][sm] = vb[q];
            ssa += va[q] * va[q];
            ssb += vb[q] * vb[q];
        }
        // same-wave LDS write->read ordering is handled by the compiler's
        // lgkmcnt waits; no barrier needed (each wave uses only its slab).
        #pragma unroll
        for (int k = 0; k < 32; ++k) {
            const float4 av = *(const float4*)&As[w][k][ty << 2];
            const float4 bv = *(const float4*)&Bs[w][k][tx << 2];
            float a_[4] = {av.x, av.y, av.z, av.w};
            float b_[4] = {bv.x, bv.y, bv.z, bv.w};
            #pragma unroll
            for (int i = 0; i < 4; ++i)
                #pragma unroll
                for (int j = 0; j < 4; ++j)
                    acc[i][j] += a_[i] * b_[j];
        }
    }

    // publish partials
    sAq[w][shalf][sm] = ssa;
    sBq[w][shalf][sm] = ssb;
    #pragma unroll
    for (int i = 0; i < 4; ++i)
        *(float4*)&comb[w][l][i * 4] =
            make_float4(acc[i][0], acc[i][1], acc[i][2], acc[i][3]);
    __syncthreads();

    if (w == 0) {
        float f[4][4];
        #pragma unroll
        for (int i = 0; i < 4; ++i) {
            float4 c0 = *(const float4*)&comb[0][l][i * 4];
            float4 c1 = *(const float4*)&comb[1][l][i * 4];
            float4 c2 = *(const float4*)&comb[2][l][i * 4];
            float4 c3 = *(const float4*)&comb[3][l][i * 4];
            f[i][0] = c0.x + c1.x + c2.x + c3.x;
            f[i][1] = c0.y + c1.y + c2.y + c3.y;
            f[i][2] = c0.z + c1.z + c2.z + c3.z;
            f[i][3] = c0.w + c1.w + c2.w + c3.w;
        }
        float inv_a[4], inv_b[4];
        #pragma unroll
        for (int i = 0; i < 4; ++i) {
            const int m = (ty << 2) + i;
            const int n = (tx << 2) + i;
            float sa = 0.f, sb = 0.f;
            #pragma unroll
            for (int ww = 0; ww < 4; ++ww) {
                sa += sAq[ww][0][m] + sAq[ww][1][m];
                sb += sBq[ww][0][n] + sBq[ww][1][n];
            }
            inv_a[i] = 1.0f / fmaxf(sqrtf(sa), 1e-12f);
            inv_b[i] = 1.0f / fmaxf(sqrtf(sb), 1e-12f);
        }
        #pragma unroll
        for (int i = 0; i < 4; ++i) {
            float4 o;
            o.x = sqrtf(fmaxf(2.0f - 2.0f * f[i][0] * inv_a[i] * inv_b[0], 0.0f));
            o.y = sqrtf(fmaxf(2.0f - 2.0f * f[i][1] * inv_a[i] * inv_b[1], 0.0f));
            o.z = sqrtf(fmaxf(2.0f - 2.0f * f[i][2] * inv_a[i] * inv_b[2], 0.0f));
            o.w = sqrtf(fmaxf(2.0f - 2.0f * f[i][3] * inv_a[i] * inv_b[3], 0.0f));
            *(float4*)&dist[(size_t)(brow + (ty << 2) + i) * BSZ + bcol + (tx << 2)] = o;
        }
    }
}

// ------- Kernel 2: ranked-list counting + last-block final reduce -----
// grid = 512 blocks (one per anchor i), block = 256 threads (4 waves).
__global__ void rll_count(const float* __restrict__ dist,
                          const int* __restrict__ labels,
                          float* __restrict__ partial,
                          int* __restrict__ counter,
                          float* __restrict__ out) {
    __shared__ float dsh[BSZ];
    __shared__ int   lsh[BSZ];
    __shared__ int   pos[BSZ];
    __shared__ int   npos;
    __shared__ float wsum[4];
    __shared__ bool  last;
    const int i = blockIdx.x;
    const int tid = threadIdx.x;
    if (tid == 0) npos = 0;
    if (tid < 128) {
        const float4 d4 = ((const float4*)(dist + (size_t)i * BSZ))[tid];
        *(float4*)&dsh[tid * 4] = d4;
        const int4 l4 = ((const int4*)labels)[tid];
        *(int4*)&lsh[tid * 4] = l4;
    }
    __syncthreads();
    const int li = lsh[i];
    for (int j = tid; j < BSZ; j += 256) {
        if (j != i && lsh[j] == li) {
            int idx = atomicAdd(&npos, 1);
            pos[idx] = j;
        }
    }
    if (tid < 4) wsum[tid] = 0.f;
    __syncthreads();
    const int wave = tid >> 6, lane = tid & 63;
    const int np = npos;
    float acc = 0.f;
    for (int p = wave; p < np; p += 4) {
        const int j = pos[p];
        const float thr = dsh[j] + MARGIN;
        int cnt = 0;
        #pragma unroll
        for (int kk = 0; kk < BSZ / 64; ++kk) {
            const int k = lane + kk * 64;
            cnt += (lsh[k] != li && dsh[k] < thr) ? 1 : 0;
        }
        #pragma unroll
        for (int off = 32; off > 0; off >>= 1) cnt += __shfl_down(cnt, off);
        if (lane == 0 && cnt > 0) acc += log1pf((float)cnt);
    }
    if (lane == 0) wsum[wave] = acc;
    __syncthreads();
    if (tid == 0) {
        partial[i] = wsum[0] + wsum[1] + wsum[2] + wsum[3];
        __threadfence();                       // make partial visible device-wide
        const int old = atomicAdd(counter, 1); // device-scope
        last = (old == BSZ - 1);
    }
    __syncthreads();
    if (last) {
        __threadfence();                       // acquire: see all partials
        if (tid < 64) {
            volatile const float* vp = (volatile const float*)partial;
            float s = 0.f;
            #pragma unroll
            for (int q = 0; q < BSZ / 64; ++q) s += vp[tid + q * 64];
            #pragma unroll
            for (int off = 32; off > 0; off >>= 1) s += __shfl_down(s, off);
            if (tid == 0) out[0] = s * (ALPHA / (512.0f + 1e-8f));
        }
    }
}

extern "C" void kernel_launch(void* const* d_in, const int* in_sizes, int n_in,
                              void* d_out, int out_size, void* d_ws, size_t ws_size,
                              hipStream_t stream) {
    const float* emb    = (const float*)d_in[0];
    const int*   labels = (const int*)d_in[1];
    float* out = (float*)d_out;

    // workspace layout: dist (512*512 f32) | partial (512 f32) | counter (int)
    float* dist    = (float*)d_ws;
    float* partial = dist + (size_t)BSZ * BSZ;
    int*   counter = (int*)(partial + BSZ);

    dim3 gd(BSZ / 32, BSZ / 32);
    rll_dist<<<gd, 256, 0, stream>>>(emb, dist, counter);

    rll_count<<<BSZ, 256, 0, stream>>>(dist, labels, partial, counter, out);
}